// Round 1
// baseline (784.141 us; speedup 1.0000x reference)
//
#include <hip/hip_runtime.h>
#include <math.h>

// Problem constants
#define B_ 64
#define LS_ 1024
#define H_ 512

// ws layout (in floats)
#define OFF_AT    0u
#define SZ_AT     (1024u*2048u)
#define OFF_YSTAT (OFF_AT + SZ_AT)
#define SZ_YSTAT  (3u*16u*512u)
#define OFF_STAT  (OFF_YSTAT + SZ_YSTAT)
#define SZ_STAT   (3u*1024u*512u)
#define OFF_PHI   (OFF_STAT + SZ_STAT)
#define SZ_PHI    (64u*1024u)
#define OFF_CS    (OFF_PHI + SZ_PHI)
#define SZ_CS     (64u*2048u)
#define OFF_DYNP  (OFF_CS + SZ_CS)
#define SZ_DYNP   (8u*3u*64u*512u)
#define OFF_HW    (OFF_DYNP + SZ_DYNP)
#define SZ_HW     (64u*512u)
#define OFF_SUMC  (OFF_HW + SZ_HW)
#define SZ_SUMC   64u
#define OFF_ETAP  (OFF_SUMC + SZ_SUMC)
#define SZ_ETAP   (4u*64u*1024u)

#define OUT_S_FLOATS (64u*11u*1024u*2u)   // 1441792
#define OUT_MU_FLOATS (64u*10u*16u)       // 10240

// ---------------------------------------------------------------------------
// AT[bm][k]: k<1024 -> w_re[b][k][m]; k in [1024,2048) -> w_im[b][k-1024][m]
// grid (64 b, 16 ltiles, 2 re/im), block 256
__global__ __launch_bounds__(256) void k_transpose(
    const float* __restrict__ wre, const float* __restrict__ wim,
    float* __restrict__ AT) {
  __shared__ float tile[64][17];
  int b = blockIdx.x, l0 = blockIdx.y * 64;
  const float* src = blockIdx.z ? wim : wre;
  int koff = blockIdx.z ? 1024 : 0;
  // load 64 l x 16 m = 1024 contiguous floats (m fastest)
  {
    int i4 = threadIdx.x * 4;
    int l = i4 >> 4, m = i4 & 15;
    float4 v = *(const float4*)(src + ((size_t)b * 1024 + l0 + l) * 16 + m);
    tile[l][m] = v.x; tile[l][m + 1] = v.y; tile[l][m + 2] = v.z; tile[l][m + 3] = v.w;
  }
  __syncthreads();
  // write: row (b*16+m), cols l0..l0+63, float4 along l
  {
    int i4 = threadIdx.x * 4;
    int l = i4 & 63, m = i4 >> 6;
    float4 o;
    o.x = tile[l + 0][m]; o.y = tile[l + 1][m];
    o.z = tile[l + 2][m]; o.w = tile[l + 3][m];
    *(float4*)(AT + ((size_t)(b * 16 + m)) * 2048 + koff + l0 + l) = o;
  }
}

// ---------------------------------------------------------------------------
// ystat[mlp][m][h] = b1[h] + sum_{l<2048} y[l*16+m] * W1[(4096+l)*512 + h]
// grid (3, 16), block 512
__global__ __launch_bounds__(512) void k_ystat(
    const float* __restrict__ y,
    const float* __restrict__ eW1, const float* __restrict__ eb1,
    const float* __restrict__ rW1, const float* __restrict__ rb1,
    const float* __restrict__ mW1, const float* __restrict__ mb1,
    float* __restrict__ ystat) {
  int mlp = blockIdx.x, m = blockIdx.y, h = threadIdx.x;
  const float* W1 = (mlp == 0) ? eW1 : (mlp == 1) ? rW1 : mW1;
  const float* b1 = (mlp == 0) ? eb1 : (mlp == 1) ? rb1 : mb1;
  const float* Wp = W1 + 4096u * 512u + h;
  float acc = b1[h];
  #pragma unroll 8
  for (int l = 0; l < 2048; ++l)
    acc = fmaf(y[l * 16 + m], Wp[(size_t)l * 512], acc);
  ystat[((size_t)mlp * 16 + m) * 512 + h] = acc;
}

// ---------------------------------------------------------------------------
// stat[mlp][bm][h] = sum_{k<2048} AT[bm][k]*W1[(2048+k)*512+h] + ystat[mlp][bm&15][h]
// grid (16 mtiles, 8 ntiles, 3 mlp), block 256, 64x64 tile, 4x4 microtile
__global__ __launch_bounds__(256) void k_static_gemm(
    const float* __restrict__ AT,
    const float* __restrict__ eW1, const float* __restrict__ rW1,
    const float* __restrict__ mW1,
    const float* __restrict__ ystat, float* __restrict__ stat) {
  int mlp = blockIdx.z;
  const float* W1 = (mlp == 0) ? eW1 : (mlp == 1) ? rW1 : mW1;
  int m0 = blockIdx.x * 64, n0 = blockIdx.y * 64;
  const float* Bbase = W1 + 2048u * 512u + n0;
  __shared__ float As[16][64];
  __shared__ float Bs[16][64];
  int tid = threadIdx.x;
  int ty = tid >> 4, tx = tid & 15;
  int arow = tid >> 2, akk = (tid & 3) << 2;
  int bkk = tid >> 4, bnn = (tid & 15) << 2;
  float acc[4][4] = {};
  for (int k0 = 0; k0 < 2048; k0 += 16) {
    float4 av = *(const float4*)(AT + ((size_t)(m0 + arow)) * 2048 + k0 + akk);
    float4 bv = *(const float4*)(Bbase + ((size_t)(k0 + bkk)) * 512 + bnn);
    As[akk + 0][arow] = av.x; As[akk + 1][arow] = av.y;
    As[akk + 2][arow] = av.z; As[akk + 3][arow] = av.w;
    *(float4*)&Bs[bkk][bnn] = bv;
    __syncthreads();
    #pragma unroll
    for (int k = 0; k < 16; ++k) {
      float4 a = *(const float4*)&As[k][ty << 2];
      float4 bb = *(const float4*)&Bs[k][tx << 2];
      float ar[4] = {a.x, a.y, a.z, a.w};
      float br[4] = {bb.x, bb.y, bb.z, bb.w};
      #pragma unroll
      for (int i = 0; i < 4; ++i)
        #pragma unroll
        for (int j = 0; j < 4; ++j)
          acc[i][j] = fmaf(ar[i], br[j], acc[i][j]);
    }
    __syncthreads();
  }
  #pragma unroll
  for (int i = 0; i < 4; ++i) {
    int bm = m0 + (ty << 2) + i;
    const float* ys = ystat + ((size_t)mlp * 16 + (bm & 15)) * 512 + n0;
    float* cp = stat + ((size_t)mlp * 1024 + bm) * 512 + n0;
    #pragma unroll
    for (int j = 0; j < 4; ++j)
      cp[(tx << 2) + j] = acc[i][j] + ys[(tx << 2) + j];
  }
}

// ---------------------------------------------------------------------------
// Generic 64-row GEMM partial: C[(blockIdx.y*gridDim.z+blockIdx.z)*64 + r][n]
//   = sum_{k in slab} A[r][k] * B[k][n]   (C row stride == ldb)
// block 256, 64x64 tile, 4x4 microtile
__global__ __launch_bounds__(256) void k_gemm64(
    const float* __restrict__ A, int lda,
    const float* __restrict__ B0, const float* __restrict__ B1,
    const float* __restrict__ B2, int ldb,
    float* __restrict__ C, int Kslab) {
  const float* Bp = (blockIdx.z == 0) ? B0 : (blockIdx.z == 1) ? B1 : B2;
  int n0 = blockIdx.x * 64;
  int kbase = blockIdx.y * Kslab;
  __shared__ float As[16][64];
  __shared__ float Bs[16][64];
  int tid = threadIdx.x;
  int ty = tid >> 4, tx = tid & 15;
  int arow = tid >> 2, akk = (tid & 3) << 2;
  int bkk = tid >> 4, bnn = (tid & 15) << 2;
  float acc[4][4] = {};
  for (int k0 = kbase; k0 < kbase + Kslab; k0 += 16) {
    float4 av = *(const float4*)(A + (size_t)arow * lda + k0 + akk);
    float4 bv = *(const float4*)(Bp + ((size_t)(k0 + bkk)) * ldb + n0 + bnn);
    As[akk + 0][arow] = av.x; As[akk + 1][arow] = av.y;
    As[akk + 2][arow] = av.z; As[akk + 3][arow] = av.w;
    *(float4*)&Bs[bkk][bnn] = bv;
    __syncthreads();
    #pragma unroll
    for (int k = 0; k < 16; ++k) {
      float4 a = *(const float4*)&As[k][ty << 2];
      float4 bb = *(const float4*)&Bs[k][tx << 2];
      float ar[4] = {a.x, a.y, a.z, a.w};
      float br[4] = {bb.x, bb.y, bb.z, bb.w};
      #pragma unroll
      for (int i = 0; i < 4; ++i)
        #pragma unroll
        for (int j = 0; j < 4; ++j)
          acc[i][j] = fmaf(ar[i], br[j], acc[i][j]);
    }
    __syncthreads();
  }
  int chunk = blockIdx.y * gridDim.z + blockIdx.z;
  float* Cp = C + ((size_t)chunk * 64) * ldb + n0;
  #pragma unroll
  for (int i = 0; i < 4; ++i)
    #pragma unroll
    for (int j = 0; j < 4; ++j)
      Cp[((size_t)((ty << 2) + i)) * ldb + (tx << 2) + j] = acc[i][j];
}

// ---------------------------------------------------------------------------
// init: phi = phi0; cs = [cos|sin]; out slot 0; zero mu_stack
// grid 296 (256 main + 40 mu-zero), block 256
__global__ __launch_bounds__(256) void k_init(
    const float* __restrict__ phi0, float* __restrict__ phi,
    float* __restrict__ cs, float* __restrict__ out) {
  int bid = blockIdx.x;
  if (bid < 256) {
    int i = bid * 256 + threadIdx.x;
    float p = phi0[i];
    phi[i] = p;
    int b = i >> 10, k = i & 1023;
    float sn, cn;
    sincosf(p, &sn, &cn);
    cs[(size_t)b * 2048 + k] = cn;
    cs[(size_t)b * 2048 + 1024 + k] = sn;
    size_t o = (((size_t)b * 11) * 1024 + k) * 2;
    out[o] = cn; out[o + 1] = sn;
  } else {
    int j = (bid - 256) * 256 + threadIdx.x;
    out[OUT_S_FLOATS + j] = 0.f;
  }
}

// ---------------------------------------------------------------------------
// reduce: h_x = relu(dyn_x + stat_x); rho/mu dots; hw = sum_m coeff*h_e;
// sumc = sum_m coeff.   grid 64 (b), block 512 (h)
__global__ __launch_bounds__(512) void k_reduce(
    const float* __restrict__ dynp, const float* __restrict__ stat,
    const float* __restrict__ rW2, const float* __restrict__ rb2,
    const float* __restrict__ mW2, const float* __restrict__ mb2,
    float* __restrict__ hw, float* __restrict__ sumc) {
  int b = blockIdx.x, h = threadIdx.x;
  float de = 0.f, dr = 0.f, dm = 0.f;
  #pragma unroll
  for (int s = 0; s < 8; ++s) {
    de += dynp[((size_t)((s * 3 + 0) * 64 + b)) * 512 + h];
    dr += dynp[((size_t)((s * 3 + 1) * 64 + b)) * 512 + h];
    dm += dynp[((size_t)((s * 3 + 2) * 64 + b)) * 512 + h];
  }
  float wr2 = rW2[h], wm2 = mW2[h];
  float rb = rb2[0], mb = mb2[0];
  int lane = h & 63, wave = h >> 6;
  __shared__ float s_r[8], s_m[8];
  float hwacc = 0.f, scacc = 0.f;
  const float* se_p = stat + ((size_t)(0 * 1024) + b * 16) * 512 + h;
  const float* sr_p = stat + ((size_t)(1 * 1024) + b * 16) * 512 + h;
  const float* sm_p = stat + ((size_t)(2 * 1024) + b * 16) * 512 + h;
  for (int m = 0; m < 16; ++m) {
    float he = fmaxf(de + se_p[(size_t)m * 512], 0.f);
    float hr = fmaxf(dr + sr_p[(size_t)m * 512], 0.f);
    float hm = fmaxf(dm + sm_p[(size_t)m * 512], 0.f);
    float pr = hr * wr2, pm = hm * wm2;
    #pragma unroll
    for (int off = 32; off; off >>= 1) {
      pr += __shfl_down(pr, off);
      pm += __shfl_down(pm, off);
    }
    if (lane == 0) { s_r[wave] = pr; s_m[wave] = pm; }
    __syncthreads();
    float rho = rb, mu = mb;
    #pragma unroll
    for (int w = 0; w < 8; ++w) { rho += s_r[w]; mu += s_m[w]; }
    __syncthreads();
    float coeff = rho * mu;
    hwacc = fmaf(coeff, he, hwacc);
    scacc += coeff;
  }
  hw[(size_t)b * 512 + h] = hwacc;
  if (h == 0) sumc[b] = scacc;
}

// ---------------------------------------------------------------------------
// update: eta = sum_slab etap + sumc*eb2; phi -= eta; write cs + out slot t+1
// grid 256, block 256
__global__ __launch_bounds__(256) void k_update(
    const float* __restrict__ etap, const float* __restrict__ eb2,
    const float* __restrict__ sumc, float* __restrict__ phi,
    float* __restrict__ cs, float* __restrict__ out, int t) {
  int i = blockIdx.x * 256 + threadIdx.x;
  int b = i >> 10, k = i & 1023;
  float e = sumc[b] * eb2[k];
  #pragma unroll
  for (int s = 0; s < 4; ++s)
    e += etap[((size_t)(s * 64 + b)) * 1024 + k];
  float p = phi[i] - e;
  phi[i] = p;
  float sn, cn;
  sincosf(p, &sn, &cn);
  cs[(size_t)b * 2048 + k] = cn;
  cs[(size_t)b * 2048 + 1024 + k] = sn;
  size_t o = (((size_t)(b * 11 + t + 1)) * 1024 + k) * 2;
  out[o] = cn; out[o + 1] = sn;
}

// ---------------------------------------------------------------------------
extern "C" void kernel_launch(void* const* d_in, const int* in_sizes, int n_in,
                              void* d_out, int out_size, void* d_ws, size_t ws_size,
                              hipStream_t stream) {
  const float* phi0 = (const float*)d_in[0];
  const float* wre  = (const float*)d_in[1];
  const float* wim  = (const float*)d_in[2];
  const float* y    = (const float*)d_in[3];
  const float* eW1  = (const float*)d_in[4];
  const float* eb1  = (const float*)d_in[5];
  const float* eW2  = (const float*)d_in[6];
  const float* eb2  = (const float*)d_in[7];
  const float* rW1  = (const float*)d_in[8];
  const float* rb1  = (const float*)d_in[9];
  const float* rW2  = (const float*)d_in[10];
  const float* rb2  = (const float*)d_in[11];
  const float* mW1  = (const float*)d_in[12];
  const float* mb1  = (const float*)d_in[13];
  const float* mW2  = (const float*)d_in[14];
  const float* mb2  = (const float*)d_in[15];

  float* ws    = (float*)d_ws;
  float* AT    = ws + OFF_AT;
  float* ystat = ws + OFF_YSTAT;
  float* stat  = ws + OFF_STAT;
  float* phi   = ws + OFF_PHI;
  float* cs    = ws + OFF_CS;
  float* dynp  = ws + OFF_DYNP;
  float* hw    = ws + OFF_HW;
  float* sumc  = ws + OFF_SUMC;
  float* etap  = ws + OFF_ETAP;
  float* out   = (float*)d_out;

  // Precompute (once per call)
  k_transpose<<<dim3(64, 16, 2), dim3(256), 0, stream>>>(wre, wim, AT);
  k_ystat<<<dim3(3, 16), dim3(512), 0, stream>>>(y, eW1, eb1, rW1, rb1, mW1, mb1, ystat);
  k_static_gemm<<<dim3(16, 8, 3), dim3(256), 0, stream>>>(AT, eW1, rW1, mW1, ystat, stat);
  k_init<<<dim3(296), dim3(256), 0, stream>>>(phi0, phi, cs, out);

  // Unrolled recursion
  for (int t = 0; t < 10; ++t) {
    // dyn[slab][mlp][b][h] partials: [64x2048]@[2048x512] x3, K-split 8
    k_gemm64<<<dim3(8, 8, 3), dim3(256), 0, stream>>>(
        cs, 2048, eW1, rW1, mW1, 512, dynp, 256);
    // per-b reduction: relu, rho/mu dots, hw, sumc
    k_reduce<<<dim3(64), dim3(512), 0, stream>>>(
        dynp, stat, rW2, rb2, mW2, mb2, hw, sumc);
    // eta partials: [64x512]@[512x1024], K-split 4
    k_gemm64<<<dim3(16, 4, 1), dim3(256), 0, stream>>>(
        hw, 512, eW2, eW2, eW2, 1024, etap, 128);
    // phi update + cos/sin + output slot t+1
    k_update<<<dim3(256), dim3(256), 0, stream>>>(
        etap, eb2, sumc, phi, cs, out, t);
  }
}